// Round 11
// baseline (712.552 us; speedup 1.0000x reference)
//
#include <hip/hip_runtime.h>
#include <math.h>

#define NN 20000
#define FF 32
#define TT 12
#define HH 64
#define EE 320000
#define OUTD 12
#define CT2 625    // 32-row tiles: NN/32 exactly
#define GB  2500   // NN/8 gather blocks (= 4*CT2)
#define HST 832    // hseqsT node stride = 13*64 (slot 0 = h1(-1) = zeros)
#define QS  196    // attn qtile row stride (u16): LDS 26624B -> 6 blocks/CU

typedef __attribute__((ext_vector_type(8))) short short8;
typedef __attribute__((ext_vector_type(4))) float floatx4;

// ---- fast transcendentals ----
__device__ __forceinline__ float aexp2(float x) {
    float r; asm("v_exp_f32 %0, %1" : "=v"(r) : "v"(x)); return r;
}
__device__ __forceinline__ float arcp(float x) {
    float r; asm("v_rcp_f32 %0, %1" : "=v"(r) : "v"(x)); return r;
}
#define LOG2E 1.44269504088896f
__device__ __forceinline__ float fsig(float x) { return arcp(1.f + aexp2(-LOG2E * x)); }
__device__ __forceinline__ float ftanh(float x) {
    return fmaf(-2.f, arcp(1.f + aexp2(2.f * LOG2E * x)), 1.f);
}

__device__ __forceinline__ unsigned short bf16rne(float f) {
    union { float f; unsigned u; } v; v.f = f;
    unsigned u = v.u;
    u += 0x7fffu + ((u >> 16) & 1u);
    return (unsigned short)(u >> 16);
}
__device__ __forceinline__ float lof(unsigned v) {
    union { unsigned u; float f; } x; x.u = v << 16; return x.f;
}
__device__ __forceinline__ float hif(unsigned v) {
    union { unsigned u; float f; } x; x.u = v & 0xffff0000u; return x.f;
}
__device__ __forceinline__ unsigned packbf(float a, float b) {
    return (unsigned)bf16rne(a) | ((unsigned)bf16rne(b) << 16);
}

#define MFMA(a, b, c) __builtin_amdgcn_mfma_f32_16x16x32_bf16((a), (b), (c), 0, 0, 0)

// ---------------- preprocessing ----------------

__global__ void init_all(float* deg, int* cnt, unsigned* h0s2u, unsigned* hseqTu) {
    int i = blockIdx.x * 256 + threadIdx.x;
    if (i < NN) { deg[i] = 1.0f; cnt[i] = 0; }
    if (i < NN * HH / 2) { h0s2u[i] = 0u; }
    if (i < NN * 32) { hseqTu[(size_t)(i >> 5) * (HST / 2) + (i & 31)] = 0u; }
}

__global__ void edge_accum_kernel(const int* ei, const float* ea, float* deg, int* cnt) {
    int e = blockIdx.x * 256 + threadIdx.x;
    if (e >= EE) return;
    int d = ei[EE + e];
    float w = ea[e * 2 + 1];
    atomicAdd(&deg[d], w);
    atomicAdd(&cnt[d], 1);
}

__global__ void scan_dinv(const int* cnt, int* rowptr, int* cursor,
                          const float* deg, float* dinv) {
    if (blockIdx.x != 0) {
        int i = (blockIdx.x - 1) * 1024 + threadIdx.x;
        if (i < NN) dinv[i] = rsqrtf(deg[i]);
        return;
    }
    __shared__ int wsum[16];
    int tid = threadIdx.x;
    int lane = tid & 63, w = tid >> 6;
    int run = 0;
    for (int base = 0; base < NN; base += 1024) {
        int idx = base + tid;
        int c = (idx < NN) ? cnt[idx] : 0;
        int v = c;
        #pragma unroll
        for (int off = 1; off < 64; off <<= 1) {
            int t = __shfl_up(v, off, 64);
            if (lane >= off) v += t;
        }
        if (lane == 63) wsum[w] = v;
        __syncthreads();
        if (tid < 16) {
            int x = wsum[tid];
            #pragma unroll
            for (int off = 1; off < 16; off <<= 1) {
                int t = __shfl_up(x, off, 64);
                if (tid >= off) x += t;
            }
            wsum[tid] = x;
        }
        __syncthreads();
        int waveoff = (w > 0) ? wsum[w - 1] : 0;
        int excl = run + waveoff + (v - c);
        if (idx < NN) { rowptr[idx] = excl; cursor[idx] = excl; }
        run += wsum[15];
        __syncthreads();
    }
    if (tid == 0) rowptr[NN] = run;
}

// packed CSR payload: {col, bits(norm)} in one 8B load
__global__ void fill_kernel(const int* ei, const float* ea, const float* dinv,
                            int* cursor, int2* colval) {
    int e = blockIdx.x * 256 + threadIdx.x;
    if (e >= EE) return;
    int s = ei[e], d = ei[EE + e];
    float w = ea[e * 2 + 1];
    int pos = atomicAdd(&cursor[d], 1);
    colval[pos] = make_int2(s, __float_as_int(dinv[s] * w * dinv[d]));
}

// fused: LDS-tiled transpose ([0,TPB)) + weight conversion + fold_out.
#define TPB 1250   // NN/16
#define WCB 336
__global__ void prep_misc(const float* __restrict__ x, unsigned short* __restrict__ xTs,
                          const float* Wg0, const float* Wu0, const float* Wr0, const float* Wc0,
                          const float* Wg1, const float* Wu1, const float* Wr1, const float* Wc1,
                          const float* ipw,
                          short* Wg0T, short* Wu0T, short* Wr0T, short* Wc0T,
                          short* Wg1T, short* Wu1T, short* Wr1T, short* Wc1T, short* ipwB,
                          const float* opw, const float* opb, const float* ow, const float* ob,
                          float* OW2, float* ob2) {
    int b = blockIdx.x;
    if (b < TPB) {
        __shared__ float tl[16 * 416];    // [nn][f*13 + t], 26.6 KB
        int n0 = b * 16;
        const float* xb = x + (size_t)n0 * 384;
        int tid = threadIdx.x;
        #pragma unroll
        for (int k = 0; k < 24; ++k) {
            int i = tid + 256 * k;                 // i < 6144
            float v = xb[i];
            int nn = i / 384;
            int rem = i - nn * 384;
            int f = rem / 12;
            int t2 = rem - f * 12;
            tl[nn * 416 + f * 13 + t2] = v;
        }
        __syncthreads();
        #pragma unroll
        for (int k = 0; k < 24; ++k) {
            int o = tid + 256 * k;
            int f = o & 31;
            int nn = (o >> 5) & 15;
            int t = o >> 9;
            xTs[(size_t)t * (NN * FF) + (size_t)(n0 + nn) * 32 + f] =
                bf16rne(tl[nn * 416 + f * 13 + t]);
        }
        return;
    }
    if (b < TPB + WCB) {
        int i = (b - TPB) * 256 + threadIdx.x;
        if (i < 2048) { int n = i / 32, k = i % 32; Wg0T[i] = (short)bf16rne(Wg0[k * 64 + n]); return; }
        i -= 2048;
        if (i < 10240) { int n = i / 160, k = i % 160; Wu0T[i] = (short)bf16rne(Wu0[k * 64 + n]); return; }
        i -= 10240;
        if (i < 10240) { int n = i / 160, k = i % 160; Wr0T[i] = (short)bf16rne(Wr0[k * 64 + n]); return; }
        i -= 10240;
        if (i < 10240) { int n = i / 160, k = i % 160; Wc0T[i] = (short)bf16rne(Wc0[k * 64 + n]); return; }
        i -= 10240;
        if (i < 4096) { int n = i / 64, k = i % 64; Wg1T[i] = (short)bf16rne(Wg1[k * 64 + n]); return; }
        i -= 4096;
        if (i < 12288) { int n = i / 192, k = i % 192; Wu1T[i] = (short)bf16rne(Wu1[k * 64 + n]); return; }
        i -= 12288;
        if (i < 12288) { int n = i / 192, k = i % 192; Wr1T[i] = (short)bf16rne(Wr1[k * 64 + n]); return; }
        i -= 12288;
        if (i < 12288) { int n = i / 192, k = i % 192; Wc1T[i] = (short)bf16rne(Wc1[k * 64 + n]); return; }
        i -= 12288;
        if (i < 12288) { ipwB[i] = (short)bf16rne(ipw[i]); }
        return;
    }
    {
        int i = (b - TPB - WCB) * 256 + threadIdx.x;
        if (i < 64 * OUTD) {
            int k = i / OUTD, d = i - k * OUTD;
            float acc = 0.f;
            for (int j = 0; j < 64; ++j) acc += opw[j * 64 + k] * ow[j * OUTD + d];
            OW2[i] = acc;
        } else if (i < 64 * OUTD + OUTD) {
            int d = i - 64 * OUTD;
            float acc = ob[d];
            for (int j = 0; j < 64; ++j) acc += opb[j] * ow[j * OUTD + d];
            ob2[d] = acc;
        }
    }
}

// bf16 aggregation over x planes: 16 lanes/node; unroll-16 first pass (avg degree = 16,
// so the typical node resolves in ONE round of independent loads), then 8/4/1 tails.
__global__ void gather_raw32(const unsigned short* __restrict__ xTs, const float* __restrict__ dinv,
                             const int* __restrict__ rowptr, const int2* __restrict__ colval,
                             unsigned short* __restrict__ aggxs) {
    const unsigned* src = (const unsigned*)(xTs + (size_t)blockIdx.y * NN * 32);
    unsigned* dst = (unsigned*)(aggxs + (size_t)blockIdx.y * NN * 32);
    int node = blockIdx.x * 16 + (threadIdx.x >> 4);
    int l2 = threadIdx.x & 15;
    float di = dinv[node];
    float dd = di * di;
    unsigned v = src[node * 16 + l2];
    float a0 = dd * lof(v), a1 = dd * hif(v);
    int s = rowptr[node], e = rowptr[node + 1];
    int j = s;
    for (; j + 15 < e; j += 16) {
        int2 c[16];
        #pragma unroll
        for (int q = 0; q < 16; ++q) c[q] = colval[j + q];
        unsigned vv[16];
        #pragma unroll
        for (int q = 0; q < 16; ++q) vv[q] = src[c[q].x * 16 + l2];
        #pragma unroll
        for (int q = 0; q < 16; ++q) {
            float w = __int_as_float(c[q].y);
            a0 += w * lof(vv[q]); a1 += w * hif(vv[q]);
        }
    }
    for (; j + 7 < e; j += 8) {
        int2 c[8];
        #pragma unroll
        for (int q = 0; q < 8; ++q) c[q] = colval[j + q];
        unsigned vv[8];
        #pragma unroll
        for (int q = 0; q < 8; ++q) vv[q] = src[c[q].x * 16 + l2];
        #pragma unroll
        for (int q = 0; q < 8; ++q) {
            float w = __int_as_float(c[q].y);
            a0 += w * lof(vv[q]); a1 += w * hif(vv[q]);
        }
    }
    for (; j + 3 < e; j += 4) {
        int2 cv0 = colval[j], cv1 = colval[j + 1], cv2 = colval[j + 2], cv3 = colval[j + 3];
        float w0 = __int_as_float(cv0.y), w1 = __int_as_float(cv1.y);
        float w2 = __int_as_float(cv2.y), w3 = __int_as_float(cv3.y);
        unsigned v0 = src[cv0.x * 16 + l2], v1 = src[cv1.x * 16 + l2];
        unsigned v2 = src[cv2.x * 16 + l2], v3 = src[cv3.x * 16 + l2];
        a0 += w0 * lof(v0) + w1 * lof(v1) + w2 * lof(v2) + w3 * lof(v3);
        a1 += w0 * hif(v0) + w1 * hif(v1) + w2 * hif(v2) + w3 * hif(v3);
    }
    for (; j < e; ++j) {
        int2 cv = colval[j];
        unsigned vv = src[cv.x * 16 + l2];
        float w = __int_as_float(cv.y);
        a0 += w * lof(vv); a1 += w * hif(vv);
    }
    dst[node * 16 + l2] = packbf(a0, a1);
}

// gather y0 + sigmoid -> g1: 32 lanes/node, unroll-16 first pass
__device__ __forceinline__ void gather_g1_body(
    int blk, const unsigned short* __restrict__ y0s, const float* __restrict__ dinv,
    const int* __restrict__ rowptr, const int2* __restrict__ colval,
    const float* __restrict__ bg1, unsigned short* __restrict__ g1s) {
    const unsigned* yp = (const unsigned*)y0s;
    int node = blk * 8 + (threadIdx.x >> 5);
    int l2 = threadIdx.x & 31;
    float di = dinv[node];
    float dd = di * di;
    unsigned v = yp[node * 32 + l2];
    float a0 = dd * lof(v), a1 = dd * hif(v);
    int s = rowptr[node], e = rowptr[node + 1];
    int j = s;
    for (; j + 15 < e; j += 16) {
        int2 c[16];
        #pragma unroll
        for (int q = 0; q < 16; ++q) c[q] = colval[j + q];
        unsigned vv[16];
        #pragma unroll
        for (int q = 0; q < 16; ++q) vv[q] = yp[c[q].x * 32 + l2];
        #pragma unroll
        for (int q = 0; q < 16; ++q) {
            float w = __int_as_float(c[q].y);
            a0 += w * lof(vv[q]); a1 += w * hif(vv[q]);
        }
    }
    for (; j + 7 < e; j += 8) {
        int2 c[8];
        #pragma unroll
        for (int q = 0; q < 8; ++q) c[q] = colval[j + q];
        unsigned vv[8];
        #pragma unroll
        for (int q = 0; q < 8; ++q) vv[q] = yp[c[q].x * 32 + l2];
        #pragma unroll
        for (int q = 0; q < 8; ++q) {
            float w = __int_as_float(c[q].y);
            a0 += w * lof(vv[q]); a1 += w * hif(vv[q]);
        }
    }
    for (; j + 3 < e; j += 4) {
        int2 cv0 = colval[j], cv1 = colval[j + 1], cv2 = colval[j + 2], cv3 = colval[j + 3];
        float w0 = __int_as_float(cv0.y), w1 = __int_as_float(cv1.y);
        float w2 = __int_as_float(cv2.y), w3 = __int_as_float(cv3.y);
        unsigned v0 = yp[cv0.x * 32 + l2], v1 = yp[cv1.x * 32 + l2];
        unsigned v2 = yp[cv2.x * 32 + l2], v3 = yp[cv3.x * 32 + l2];
        a0 += w0 * lof(v0) + w1 * lof(v1) + w2 * lof(v2) + w3 * lof(v3);
        a1 += w0 * hif(v0) + w1 * hif(v1) + w2 * hif(v2) + w3 * hif(v3);
    }
    for (; j < e; ++j) {
        int2 cv = colval[j];
        unsigned vv = yp[cv.x * 32 + l2];
        float w = __int_as_float(cv.y);
        a0 += w * lof(vv); a1 += w * hif(vv);
    }
    float g0v = fsig(a0 + bg1[2 * l2]);
    float g1v = fsig(a1 + bg1[2 * l2 + 1]);
    ((unsigned*)g1s)[node * 32 + l2] = packbf(g0v, g1v);
}

// ---------------- MFMA kernels ----------------
// A[m=lane&15][k=quad*8+j]; B^T[n=lane&15][k=quad*8+j]; C/D: col=lane&15, row=quad*4+reg.

__launch_bounds__(256, 4)
__global__ void mfma_g0(const unsigned short* __restrict__ aggxs, const short* __restrict__ Wg0T,
                        const float* __restrict__ bg0, unsigned short* __restrict__ g0s) {
    int tid = threadIdx.x;
    int wv = tid >> 6, lane = tid & 63;
    int quad = lane >> 4, ln = lane & 15;
    int m0 = blockIdx.x * 64 + wv * 16;
    short8 af = *reinterpret_cast<const short8*>(aggxs + (size_t)(m0 + ln) * 32 + quad * 8);
    floatx4 z = {0.f, 0.f, 0.f, 0.f};
    floatx4 acc[4] = {z, z, z, z};
    #pragma unroll
    for (int ct = 0; ct < 4; ++ct) {
        short8 bf = *reinterpret_cast<const short8*>(Wg0T + (size_t)(ct * 16 + ln) * 32 + quad * 8);
        acc[ct] = MFMA(af, bf, acc[ct]);
    }
    #pragma unroll
    for (int ct = 0; ct < 4; ++ct) {
        int col = ct * 16 + ln;
        float bb = bg0[col];
        #pragma unroll
        for (int r = 0; r < 4; ++r) {
            int row = m0 + quad * 4 + r;
            g0s[(size_t)row * 64 + col] = bf16rne(fsig(acc[ct][r] + bb));
        }
    }
}

// ---- cell bodies: 2 row-tiles per wave (32 rows/block), col-split across waves. ----

__device__ __forceinline__ void cell0_body(
    int m0, short* T,
    const unsigned short* __restrict__ xt, const unsigned short* __restrict__ g0,
    const unsigned short* __restrict__ h0s,
    const short* __restrict__ Wu0T, const short* __restrict__ Wr0T,
    const short* __restrict__ Wc0T, const short* __restrict__ Wg1T,
    const float* __restrict__ bu0, const float* __restrict__ br0,
    const float* __restrict__ bc0,
    unsigned short* __restrict__ h0ns, unsigned short* __restrict__ y0s) {
    int tid = threadIdx.x;
    int wv = tid >> 6, lane = tid & 63;
    int quad = lane >> 4, ln = lane & 15;
    int col = wv * 16 + ln;
    int a0r = m0 + ln, a1r = m0 + 16 + ln;

    short8 af0[5], af1[5];
    af0[0] = *reinterpret_cast<const short8*>(xt + (size_t)a0r * 32 + quad * 8);
    af1[0] = *reinterpret_cast<const short8*>(xt + (size_t)a1r * 32 + quad * 8);
    af0[1] = *reinterpret_cast<const short8*>(g0 + (size_t)a0r * 64 + quad * 8);
    af1[1] = *reinterpret_cast<const short8*>(g0 + (size_t)a1r * 64 + quad * 8);
    af0[2] = *reinterpret_cast<const short8*>(g0 + (size_t)a0r * 64 + 32 + quad * 8);
    af1[2] = *reinterpret_cast<const short8*>(g0 + (size_t)a1r * 64 + 32 + quad * 8);
    af0[3] = *reinterpret_cast<const short8*>(h0s + (size_t)a0r * 64 + quad * 8);
    af1[3] = *reinterpret_cast<const short8*>(h0s + (size_t)a1r * 64 + quad * 8);
    af0[4] = *reinterpret_cast<const short8*>(h0s + (size_t)a0r * 64 + 32 + quad * 8);
    af1[4] = *reinterpret_cast<const short8*>(h0s + (size_t)a1r * 64 + 32 + quad * 8);

    floatx4 z = {0.f, 0.f, 0.f, 0.f};
    floatx4 aU0 = z, aR0 = z, aU1 = z, aR1 = z;
    const short* bu = Wu0T + (size_t)col * 160;
    const short* br = Wr0T + (size_t)col * 160;
    #pragma unroll
    for (int kc = 0; kc < 5; ++kc) {
        int ko = kc * 32 + quad * 8;
        short8 wu = *reinterpret_cast<const short8*>(bu + ko);
        short8 wr = *reinterpret_cast<const short8*>(br + ko);
        aU0 = MFMA(af0[kc], wu, aU0);
        aU1 = MFMA(af1[kc], wu, aU1);
        aR0 = MFMA(af0[kc], wr, aR0);
        aR1 = MFMA(af1[kc], wr, aR1);
    }
    float bU = bu0[col], bR = br0[col];
    float uu0[4], hv0[4], uu1[4], hv1[4];
    #pragma unroll
    for (int r = 0; r < 4; ++r) {
        int g0r = m0 + quad * 4 + r, g1r = m0 + 16 + quad * 4 + r;
        uu0[r] = fsig(aU0[r] + bU);
        uu1[r] = fsig(aU1[r] + bU);
        hv0[r] = lof((unsigned)h0s[(size_t)g0r * 64 + col]);
        hv1[r] = lof((unsigned)h0s[(size_t)g1r * 64 + col]);
        T[(quad * 4 + r) * 72 + col] = (short)bf16rne(fsig(aR0[r] + bR) * hv0[r]);
        T[(16 + quad * 4 + r) * 72 + col] = (short)bf16rne(fsig(aR1[r] + bR) * hv1[r]);
    }
    __syncthreads();

    short8 p00 = *reinterpret_cast<const short8*>(T + ln * 72 + quad * 8);
    short8 p01 = *reinterpret_cast<const short8*>(T + ln * 72 + 32 + quad * 8);
    short8 p10 = *reinterpret_cast<const short8*>(T + (16 + ln) * 72 + quad * 8);
    short8 p11 = *reinterpret_cast<const short8*>(T + (16 + ln) * 72 + 32 + quad * 8);
    floatx4 aC0 = z, aC1 = z;
    const short* bc = Wc0T + (size_t)col * 160;
    #pragma unroll
    for (int kc = 0; kc < 3; ++kc) {
        short8 wc = *reinterpret_cast<const short8*>(bc + kc * 32 + quad * 8);
        aC0 = MFMA(af0[kc], wc, aC0);
        aC1 = MFMA(af1[kc], wc, aC1);
    }
    {
        short8 wc3 = *reinterpret_cast<const short8*>(bc + 96 + quad * 8);
        short8 wc4 = *reinterpret_cast<const short8*>(bc + 128 + quad * 8);
        aC0 = MFMA(p00, wc3, aC0);
        aC1 = MFMA(p10, wc3, aC1);
        aC0 = MFMA(p01, wc4, aC0);
        aC1 = MFMA(p11, wc4, aC1);
    }
    __syncthreads();   // all rh reads complete before T is overwritten with h_new

    float bC = bc0[col];
    #pragma unroll
    for (int r = 0; r < 4; ++r) {
        int g0r = m0 + quad * 4 + r, g1r = m0 + 16 + quad * 4 + r;
        float hn0 = uu0[r] * hv0[r] + (1.f - uu0[r]) * ftanh(aC0[r] + bC);
        float hn1 = uu1[r] * hv1[r] + (1.f - uu1[r]) * ftanh(aC1[r] + bC);
        unsigned short hb0 = bf16rne(hn0), hb1 = bf16rne(hn1);
        h0ns[(size_t)g0r * 64 + col] = hb0;
        h0ns[(size_t)g1r * 64 + col] = hb1;
        T[(quad * 4 + r) * 72 + col] = (short)hb0;
        T[(16 + quad * 4 + r) * 72 + col] = (short)hb1;
    }
    __syncthreads();

    short8 h00 = *reinterpret_cast<const short8*>(T + ln * 72 + quad * 8);
    short8 h01 = *reinterpret_cast<const short8*>(T + ln * 72 + 32 + quad * 8);
    short8 h10 = *reinterpret_cast<const short8*>(T + (16 + ln) * 72 + quad * 8);
    short8 h11 = *reinterpret_cast<const short8*>(T + (16 + ln) * 72 + 32 + quad * 8);
    floatx4 aY0 = z, aY1 = z;
    const short* bg = Wg1T + (size_t)col * 64;
    {
        short8 w0 = *reinterpret_cast<const short8*>(bg + quad * 8);
        short8 w1 = *reinterpret_cast<const short8*>(bg + 32 + quad * 8);
        aY0 = MFMA(h00, w0, aY0);
        aY1 = MFMA(h10, w0, aY1);
        aY0 = MFMA(h01, w1, aY0);
        aY1 = MFMA(h11, w1, aY1);
    }
    #pragma unroll
    for (int r = 0; r < 4; ++r) {
        int g0r = m0 + quad * 4 + r, g1r = m0 + 16 + quad * 4 + r;
        y0s[(size_t)g0r * 64 + col] = bf16rne(aY0[r]);
        y0s[(size_t)g1r * 64 + col] = bf16rne(aY1[r]);
    }
}

// cell1: h1 bf16 state lives in hseqsT (node-major, stride HST); in = slot t, out = slot t+1
__device__ __forceinline__ void cell1_body(
    int m0, short* T,
    const unsigned short* __restrict__ h0s, const unsigned short* __restrict__ g1s,
    const unsigned short* __restrict__ h1sT_in,
    const short* __restrict__ Wu1T, const short* __restrict__ Wr1T,
    const short* __restrict__ Wc1T,
    const float* __restrict__ bu1, const float* __restrict__ br1,
    const float* __restrict__ bc1,
    unsigned short* __restrict__ h1sT_out) {
    int tid = threadIdx.x;
    int wv = tid >> 6, lane = tid & 63;
    int quad = lane >> 4, ln = lane & 15;
    int col = wv * 16 + ln;
    int a0r = m0 + ln, a1r = m0 + 16 + ln;

    short8 af0[6], af1[6];
    af0[0] = *reinterpret_cast<const short8*>(h0s + (size_t)a0r * 64 + quad * 8);
    af1[0] = *reinterpret_cast<const short8*>(h0s + (size_t)a1r * 64 + quad * 8);
    af0[1] = *reinterpret_cast<const short8*>(h0s + (size_t)a0r * 64 + 32 + quad * 8);
    af1[1] = *reinterpret_cast<const short8*>(h0s + (size_t)a1r * 64 + 32 + quad * 8);
    af0[2] = *reinterpret_cast<const short8*>(g1s + (size_t)a0r * 64 + quad * 8);
    af1[2] = *reinterpret_cast<const short8*>(g1s + (size_t)a1r * 64 + quad * 8);
    af0[3] = *reinterpret_cast<const short8*>(g1s + (size_t)a0r * 64 + 32 + quad * 8);
    af1[3] = *reinterpret_cast<const short8*>(g1s + (size_t)a1r * 64 + 32 + quad * 8);
    af0[4] = *reinterpret_cast<const short8*>(h1sT_in + (size_t)a0r * HST + quad * 8);
    af1[4] = *reinterpret_cast<const short8*>(h1sT_in + (size_t)a1r * HST + quad * 8);
    af0[5] = *reinterpret_cast<const short8*>(h1sT_in + (size_t)a0r * HST + 32 + quad * 8);
    af1[5] = *reinterpret_cast<const short8*>(h1sT_in + (size_t)a1r * HST + 32 + quad * 8);

    floatx4 z = {0.f, 0.f, 0.f, 0.f};
    floatx4 aU0 = z, aR0 = z, aU1 = z, aR1 = z;
    const short* bu = Wu1T + (size_t)col * 192;
    const short* br = Wr1T + (size_t)col * 192;
    #pragma unroll
    for (int kc = 0; kc < 6; ++kc) {
        int ko = kc * 32 + quad * 8;
        short8 wu = *reinterpret_cast<const short8*>(bu + ko);
        short8 wr = *reinterpret_cast<const short8*>(br + ko);
        aU0 = MFMA(af0[kc], wu, aU0);
        aU1 = MFMA(af1[kc], wu, aU1);
        aR0 = MFMA(af0[kc], wr, aR0);
        aR1 = MFMA(af1[kc], wr, aR1);
    }
    float bU = bu1[col], bR = br1[col];
    float uu0[4], hv0[4], uu1[4], hv1[4];
    #pragma unroll
    for (int r = 0; r < 4; ++r) {
        int g0r = m0 + quad * 4 + r, g1r = m0 + 16 + quad * 4 + r;
        uu0[r] = fsig(aU0[r] + bU);
        uu1[r] = fsig(aU1[r] + bU);
        hv0[r] = lof((unsigned)h1sT_in[(size_t)g0r * HST + col]);
        hv1[r] = lof((unsigned)h1sT_in[(size_t)g1r * HST + col]);
        T[(quad * 4 + r) * 72 + col] = (short)bf16rne(fsig(aR0[r] + bR) * hv0[r]);
        T[(16 + quad * 4 + r) * 72 + col] = (short)bf16rne(fsig(aR1[r] + bR) * hv1[r]);
    }
    __syncthreads();

    short8 p00 = *reinterpret_cast<const short8*>(T + ln * 72 + quad * 8);
    short8 p01 = *reinterpret_cast<const short8*>(T + ln * 72 + 32 + quad * 8);
    short8 p10 = *reinterpret_cast<const short8*>(T + (16 + ln) * 72 + quad * 8);
    short8 p11 = *reinterpret_cast<const short8*>(T + (16 + ln) * 72 + 32 + quad * 8);
    floatx4 aC0 = z, aC1 = z;
    const short* bc = Wc1T + (size_t)col * 192;
    #pragma unroll
    for (int kc = 0; kc < 4; ++kc) {
        short8 wc = *reinterpret_cast<const short8*>(bc + kc * 32 + quad * 8);
        aC0 = MFMA(af0[kc], wc, aC0);
        aC1 = MFMA(af1[kc], wc, aC1);
    }
    {
        short8 wc4 = *reinterpret_cast<const short8*>(bc + 128 + quad * 8);
        short8 wc5 = *reinterpret_cast<const short8*>(bc + 160 + quad * 8);
        aC0 = MFMA(p00, wc4, aC0);
        aC1 = MFMA(p10, wc4, aC1);
        aC0 = MFMA(p01, wc5, aC0);
        aC1 = MFMA(p11, wc5, aC1);
    }

    float bC = bc1[col];
    #pragma unroll
    for (int r = 0; r < 4; ++r) {
        int g0r = m0 + quad * 4 + r, g1r = m0 + 16 + quad * 4 + r;
        float hn0 = uu0[r] * hv0[r] + (1.f - uu0[r]) * ftanh(aC0[r] + bC);
        float hn1 = uu1[r] * hv1[r] + (1.f - uu1[r]) * ftanh(aC1[r] + bC);
        h1sT_out[(size_t)g0r * HST + col] = bf16rne(hn0);
        h1sT_out[(size_t)g1r * HST + col] = bf16rne(hn1);
    }
}

// ---------------- 3-stage pipelined step, phase-INTERLEAVED grid ----------------

struct PipeArgs {
    const float* dinv; const int* rowptr; const int2* colval;
    const short* Wu0T; const short* Wr0T; const short* Wc0T; const short* Wg1T;
    const float* bu0; const float* br0; const float* bc0;
    const short* Wu1T; const short* Wr1T; const short* Wc1T;
    const float* bu1; const float* br1; const float* bc1; const float* bg1;
    int c0n;   // 625 or 0 (32-row tiles)
    const unsigned short* c0_xt; const unsigned short* c0_g0;
    const unsigned short* c0_hs_in;
    unsigned short* c0_hs_out; unsigned short* c0_y0_out;
    int gn;    // 2500 or 0
    const unsigned short* g_y0; unsigned short* g_g1;
    int c1n;   // 625 or 0
    const unsigned short* c1_h0s; const unsigned short* c1_g1;
    const unsigned short* c1_hsT_in;
    unsigned short* c1_hsT_out;
};

__launch_bounds__(256, 6)
__global__ void pipe_step(PipeArgs A) {
    __shared__ short T[32 * 72];
    int per = (A.c0n ? 1 : 0) + (A.gn ? 4 : 0) + (A.c1n ? 1 : 0);
    int q = blockIdx.x / per;
    int r = blockIdx.x - q * per;
    int goff = A.c0n ? 1 : 0;
    if (A.c0n && r == 0) {
        cell0_body(q * 32, T, A.c0_xt, A.c0_g0, A.c0_hs_in,
                   A.Wu0T, A.Wr0T, A.Wc0T, A.Wg1T, A.bu0, A.br0, A.bc0,
                   A.c0_hs_out, A.c0_y0_out);
        return;
    }
    if (A.gn && r >= goff && r < goff + 4) {
        gather_g1_body(q * 4 + (r - goff), A.g_y0, A.dinv, A.rowptr, A.colval, A.bg1, A.g_g1);
        return;
    }
    cell1_body(q * 32, T, A.c1_h0s, A.c1_g1, A.c1_hsT_in,
               A.Wu1T, A.Wr1T, A.Wc1T, A.bu1, A.br1, A.bc1,
               A.c1_hsT_out);
}

// ---------------- fused qkv + attention: one wave per node ----------------
__launch_bounds__(256, 6)
__global__ void attn_fused(const unsigned short* __restrict__ hseqT,
                           const short* __restrict__ ipwB, const float* __restrict__ ipb,
                           const float* __restrict__ OW2, const float* __restrict__ ob2,
                           float* __restrict__ out) {
    __shared__ __align__(16) unsigned short qtile[4][16 * QS];
    __shared__ float fbuf[4][64];
    __shared__ float wbuf[4][32];
    int wv = threadIdx.x >> 6, lane = threadIdx.x & 63;
    int node = blockIdx.x * 4 + wv;
    int quad = lane >> 4, ln = lane & 15;
    unsigned short* q = qtile[wv];
    float* sob = fbuf[wv];
    float* W = wbuf[wv];

    short8 zero8 = {0, 0, 0, 0, 0, 0, 0, 0};
    short8 af0 = zero8, af1 = zero8;
    if (ln < TT) {
        const unsigned short* hp = hseqT + (size_t)node * HST + (size_t)(ln + 1) * 64;
        af0 = *reinterpret_cast<const short8*>(hp + quad * 8);
        af1 = *reinterpret_cast<const short8*>(hp + 32 + quad * 8);
    }
    floatx4 z = {0.f, 0.f, 0.f, 0.f};
    #pragma unroll
    for (int ct = 0; ct < 12; ++ct) {
        const short* br = ipwB + (size_t)(ct * 16 + ln) * 64;
        floatx4 acc = MFMA(af0, *reinterpret_cast<const short8*>(br + quad * 8), z);
        acc = MFMA(af1, *reinterpret_cast<const short8*>(br + 32 + quad * 8), acc);
        int col = ct * 16 + ln;
        float bb = ipb[col];
        #pragma unroll
        for (int r = 0; r < 4; ++r)
            q[(quad * 4 + r) * QS + col] = bf16rne(acc[r] + bb);
    }
    __threadfence_block();

    floatx4 sc[2];
    #pragma unroll
    for (int h = 0; h < 2; ++h) {
        short8 aQ = *reinterpret_cast<const short8*>(q + ln * QS + h * 32 + quad * 8);
        short8 bK = *reinterpret_cast<const short8*>(q + ln * QS + 64 + h * 32 + quad * 8);
        sc[h] = MFMA(aQ, bK, z);
    }
    // softmax without max-subtraction (|h|<=1 by gating => |scores| bounded << 88)
    const float scl = 0.17677669529663687f;
    bool colok = ln < 12;
    #pragma unroll
    for (int h = 0; h < 2; ++h) {
        float p[4];
        #pragma unroll
        for (int r = 0; r < 4; ++r) {
            float e = colok ? aexp2(LOG2E * scl * sc[h][r]) : 0.f;
            float s = e;
            s += __shfl_xor(s, 1, 64);
            s += __shfl_xor(s, 2, 64);
            s += __shfl_xor(s, 4, 64);
            s += __shfl_xor(s, 8, 64);
            p[r] = e * arcp(s);
        }
        float ts = (quad < 3) ? (p[0] + p[1] + p[2] + p[3]) : 0.f;
        ts += __shfl_xor(ts, 16, 64);
        ts += __shfl_xor(ts, 32, 64);
        if (quad == 0) W[h * 16 + ln] = ts * (1.f / 12.f);
    }
    __threadfence_block();

    {
        int d = lane, hd = d >> 5, dd = d & 31;
        float acc = 0.f;
        #pragma unroll
        for (int ts = 0; ts < 12; ++ts)
            acc += W[hd * 16 + ts] * lof((unsigned)q[ts * QS + 128 + hd * 32 + dd]);
        sob[d] = acc;
    }
    __threadfence_block();

    // quad-split projection: quad covers k in [16*quad, 16*quad+16); reduce via 2 shuffles.
    {
        float acc = 0.f;
        if (ln < OUTD) {
            int k0 = quad * 16;
            #pragma unroll
            for (int k = 0; k < 16; ++k)
                acc = fmaf(sob[k0 + k], OW2[(k0 + k) * OUTD + ln], acc);
        }
        acc += __shfl_xor(acc, 16, 64);
        acc += __shfl_xor(acc, 32, 64);
        if (quad == 0 && ln < OUTD)
            out[(size_t)node * OUTD + ln] = acc + ob2[ln];
    }
}

// ---------------- launcher ----------------

extern "C" void kernel_launch(void* const* d_in, const int* in_sizes, int n_in,
                              void* d_out, int out_size, void* d_ws, size_t ws_size,
                              hipStream_t stream) {
    const float* x   = (const float*)d_in[0];
    const int*   ei  = (const int*)d_in[1];
    const float* ea  = (const float*)d_in[2];
    const float* Wg0 = (const float*)d_in[3];
    const float* bg0 = (const float*)d_in[4];
    const float* Wu0 = (const float*)d_in[5];
    const float* bu0 = (const float*)d_in[6];
    const float* Wr0 = (const float*)d_in[7];
    const float* br0 = (const float*)d_in[8];
    const float* Wc0 = (const float*)d_in[9];
    const float* bc0 = (const float*)d_in[10];
    const float* Wg1 = (const float*)d_in[11];
    const float* bg1 = (const float*)d_in[12];
    const float* Wu1 = (const float*)d_in[13];
    const float* bu1 = (const float*)d_in[14];
    const float* Wr1 = (const float*)d_in[15];
    const float* br1 = (const float*)d_in[16];
    const float* Wc1 = (const float*)d_in[17];
    const float* bc1 = (const float*)d_in[18];
    const float* ipw = (const float*)d_in[19];
    const float* ipb = (const float*)d_in[20];
    const float* opw = (const float*)d_in[21];
    const float* opb = (const float*)d_in[22];
    const float* ow  = (const float*)d_in[23];
    const float* ob  = (const float*)d_in[24];
    float* out = (float*)d_out;

    char* p = (char*)d_ws;
    auto alloc = [&](size_t bytes) { char* r = p; p += (bytes + 255) & ~(size_t)255; return (void*)r; };
    unsigned short* hseqT = (unsigned short*)alloc((size_t)NN * HST * 2);   // [node][13][64]
    short* Wg0T = (short*)alloc((size_t)64 * 32 * 2);
    short* Wu0T = (short*)alloc((size_t)64 * 160 * 2);
    short* Wr0T = (short*)alloc((size_t)64 * 160 * 2);
    short* Wc0T = (short*)alloc((size_t)64 * 160 * 2);
    short* Wg1T = (short*)alloc((size_t)64 * 64 * 2);
    short* Wu1T = (short*)alloc((size_t)64 * 192 * 2);
    short* Wr1T = (short*)alloc((size_t)64 * 192 * 2);
    short* Wc1T = (short*)alloc((size_t)64 * 192 * 2);
    short* ipwB = (short*)alloc((size_t)192 * 64 * 2);
    float* OW2  = (float*)alloc((size_t)64 * OUTD * 4);
    float* ob2  = (float*)alloc((size_t)OUTD * 4);
    float* dinv   = (float*)alloc((size_t)NN * 4);
    int*   rowptr = (int*)  alloc((size_t)(NN + 1) * 4);
    int2*  colval = (int2*) alloc((size_t)EE * 8);
    unsigned short* xTs   = (unsigned short*)alloc((size_t)TT * NN * FF * 2);
    unsigned short* aggxs = (unsigned short*)alloc((size_t)TT * NN * FF * 2);
    unsigned short* g0s   = (unsigned short*)alloc((size_t)TT * NN * HH * 2);
    float* deg    = (float*)alloc((size_t)NN * 4);
    int*   cnt    = (int*)  alloc((size_t)NN * 4);
    int*   cursor = (int*)  alloc((size_t)NN * 4);
    unsigned short* y0sA = (unsigned short*)alloc((size_t)NN * HH * 2);
    unsigned short* y0sB = (unsigned short*)alloc((size_t)NN * HH * 2);
    unsigned short* g1sA = (unsigned short*)alloc((size_t)NN * HH * 2);
    unsigned short* g1sB = (unsigned short*)alloc((size_t)NN * HH * 2);
    unsigned short* h0s0 = (unsigned short*)alloc((size_t)NN * HH * 2);
    unsigned short* h0s1 = (unsigned short*)alloc((size_t)NN * HH * 2);
    unsigned short* h0s2 = (unsigned short*)alloc((size_t)NN * HH * 2);
    (void)ws_size;

    init_all<<<(NN * HH + 255) / 256, 256, 0, stream>>>(
        deg, cnt, (unsigned*)h0s2, (unsigned*)hseqT);
    edge_accum_kernel<<<(EE + 255) / 256, 256, 0, stream>>>(ei, ea, deg, cnt);
    scan_dinv<<<1 + (NN + 1023) / 1024, 1024, 0, stream>>>(cnt, rowptr, cursor, deg, dinv);
    fill_kernel<<<(EE + 255) / 256, 256, 0, stream>>>(ei, ea, dinv, cursor, colval);
    prep_misc<<<TPB + WCB + 4, 256, 0, stream>>>(
        x, xTs,
        Wg0, Wu0, Wr0, Wc0, Wg1, Wu1, Wr1, Wc1, ipw,
        Wg0T, Wu0T, Wr0T, Wc0T, Wg1T, Wu1T, Wr1T, Wc1T, ipwB,
        opw, opb, ow, ob, OW2, ob2);

    gather_raw32<<<dim3(NN / 16, TT), 256, 0, stream>>>(xTs, dinv, rowptr, colval, aggxs);
    mfma_g0<<<(TT * NN) / 64, 256, 0, stream>>>(aggxs, Wg0T, bg0, g0s);

    unsigned short* h0sB[3] = {h0s0, h0s1, h0s2};
    unsigned short* y0B[2] = {y0sA, y0sB};
    unsigned short* g1B[2] = {g1sA, g1sB};

    PipeArgs base;
    base.dinv = dinv; base.rowptr = rowptr; base.colval = colval;
    base.Wu0T = Wu0T; base.Wr0T = Wr0T; base.Wc0T = Wc0T; base.Wg1T = Wg1T;
    base.bu0 = bu0; base.br0 = br0; base.bc0 = bc0;
    base.Wu1T = Wu1T; base.Wr1T = Wr1T; base.Wc1T = Wc1T;
    base.bu1 = bu1; base.br1 = br1; base.bc1 = bc1; base.bg1 = bg1;

    // pipeline: launch l = { C0(l), G(l-1), C1(l-2) }, l = 0..13
    for (int l = 0; l <= TT + 1; ++l) {
        PipeArgs A = base;
        int tc0 = l, tg = l - 1, tc1 = l - 2;

        A.c0n = (tc0 < TT) ? CT2 : 0;
        if (A.c0n) {
            A.c0_xt = xTs + (size_t)tc0 * NN * FF;
            A.c0_g0 = g0s + (size_t)tc0 * NN * HH;
            A.c0_hs_in = h0sB[(tc0 + 2) % 3];
            A.c0_hs_out = h0sB[tc0 % 3];
            A.c0_y0_out = y0B[tc0 & 1];
        } else {
            A.c0_xt = xTs; A.c0_g0 = g0s; A.c0_hs_in = h0sB[0];
            A.c0_hs_out = h0sB[0]; A.c0_y0_out = y0B[0];
        }

        A.gn = (tg >= 0 && tg < TT) ? GB : 0;
        if (A.gn) { A.g_y0 = y0B[tg & 1]; A.g_g1 = g1B[tg & 1]; }
        else { A.g_y0 = y0B[0]; A.g_g1 = g1B[0]; }

        A.c1n = (tc1 >= 0 && tc1 < TT) ? CT2 : 0;
        if (A.c1n) {
            A.c1_h0s = h0sB[tc1 % 3];
            A.c1_g1 = g1B[tc1 & 1];
            A.c1_hsT_in = hseqT + (size_t)tc1 * 64;         // slot(t-1) = tc1
            A.c1_hsT_out = hseqT + (size_t)(tc1 + 1) * 64;  // slot(t) = tc1+1
        } else {
            A.c1_h0s = h0sB[0]; A.c1_g1 = g1B[0];
            A.c1_hsT_in = hseqT; A.c1_hsT_out = hseqT;
        }

        int grid = A.c0n + A.gn + A.c1n;
        pipe_step<<<grid, 256, 0, stream>>>(A);
    }

    attn_fused<<<NN / 4, 256, 0, stream>>>(hseqT, ipwB, ipb, OW2, ob2, out);
}

// Round 12
// 702.515 us; speedup vs baseline: 1.0143x; 1.0143x over previous
//
#include <hip/hip_runtime.h>
#include <math.h>

#define NN 20000
#define FF 32
#define TT 12
#define HH 64
#define EE 320000
#define OUTD 12
#define CT2 625    // 32-row tiles: NN/32 exactly
#define GB  2500   // NN/8 gather blocks (= 4*CT2)
#define HST 832    // hseqsT node stride = 13*64 (slot 0 = h1(-1) = zeros)
#define QS  196    // attn qtile row stride (u16): LDS 26624B -> 6 blocks/CU

typedef __attribute__((ext_vector_type(8))) short short8;
typedef __attribute__((ext_vector_type(4))) float floatx4;

// ---- fast transcendentals ----
__device__ __forceinline__ float aexp2(float x) {
    float r; asm("v_exp_f32 %0, %1" : "=v"(r) : "v"(x)); return r;
}
__device__ __forceinline__ float arcp(float x) {
    float r; asm("v_rcp_f32 %0, %1" : "=v"(r) : "v"(x)); return r;
}
#define LOG2E 1.44269504088896f
__device__ __forceinline__ float fsig(float x) { return arcp(1.f + aexp2(-LOG2E * x)); }
__device__ __forceinline__ float ftanh(float x) {
    return fmaf(-2.f, arcp(1.f + aexp2(2.f * LOG2E * x)), 1.f);
}

__device__ __forceinline__ unsigned short bf16rne(float f) {
    union { float f; unsigned u; } v; v.f = f;
    unsigned u = v.u;
    u += 0x7fffu + ((u >> 16) & 1u);
    return (unsigned short)(u >> 16);
}
__device__ __forceinline__ float lof(unsigned v) {
    union { unsigned u; float f; } x; x.u = v << 16; return x.f;
}
__device__ __forceinline__ float hif(unsigned v) {
    union { unsigned u; float f; } x; x.u = v & 0xffff0000u; return x.f;
}
__device__ __forceinline__ unsigned packbf(float a, float b) {
    return (unsigned)bf16rne(a) | ((unsigned)bf16rne(b) << 16);
}

#define MFMA(a, b, c) __builtin_amdgcn_mfma_f32_16x16x32_bf16((a), (b), (c), 0, 0, 0)

// ---------------- preprocessing ----------------

__global__ void init_all(float* deg, int* cnt, unsigned* h0s2u, unsigned* hseqTu) {
    int i = blockIdx.x * 256 + threadIdx.x;
    if (i < NN) { deg[i] = 1.0f; cnt[i] = 0; }
    if (i < NN * HH / 2) { h0s2u[i] = 0u; }
    if (i < NN * 32) { hseqTu[(size_t)(i >> 5) * (HST / 2) + (i & 31)] = 0u; }
}

__global__ void edge_accum_kernel(const int* ei, const float* ea, float* deg, int* cnt) {
    int e = blockIdx.x * 256 + threadIdx.x;
    if (e >= EE) return;
    int d = ei[EE + e];
    float w = ea[e * 2 + 1];
    atomicAdd(&deg[d], w);
    atomicAdd(&cnt[d], 1);
}

__global__ void scan_dinv(const int* cnt, int* rowptr, int* cursor,
                          const float* deg, float* dinv) {
    if (blockIdx.x != 0) {
        int i = (blockIdx.x - 1) * 1024 + threadIdx.x;
        if (i < NN) dinv[i] = rsqrtf(deg[i]);
        return;
    }
    __shared__ int wsum[16];
    int tid = threadIdx.x;
    int lane = tid & 63, w = tid >> 6;
    int run = 0;
    for (int base = 0; base < NN; base += 1024) {
        int idx = base + tid;
        int c = (idx < NN) ? cnt[idx] : 0;
        int v = c;
        #pragma unroll
        for (int off = 1; off < 64; off <<= 1) {
            int t = __shfl_up(v, off, 64);
            if (lane >= off) v += t;
        }
        if (lane == 63) wsum[w] = v;
        __syncthreads();
        if (tid < 16) {
            int x = wsum[tid];
            #pragma unroll
            for (int off = 1; off < 16; off <<= 1) {
                int t = __shfl_up(x, off, 64);
                if (tid >= off) x += t;
            }
            wsum[tid] = x;
        }
        __syncthreads();
        int waveoff = (w > 0) ? wsum[w - 1] : 0;
        int excl = run + waveoff + (v - c);
        if (idx < NN) { rowptr[idx] = excl; cursor[idx] = excl; }
        run += wsum[15];
        __syncthreads();
    }
    if (tid == 0) rowptr[NN] = run;
}

// packed CSR payload: {col, bits(norm)} in one 8B load
__global__ void fill_kernel(const int* ei, const float* ea, const float* dinv,
                            int* cursor, int2* colval) {
    int e = blockIdx.x * 256 + threadIdx.x;
    if (e >= EE) return;
    int s = ei[e], d = ei[EE + e];
    float w = ea[e * 2 + 1];
    int pos = atomicAdd(&cursor[d], 1);
    colval[pos] = make_int2(s, __float_as_int(dinv[s] * w * dinv[d]));
}

// fused: LDS-tiled transpose ([0,TPB)) + weight conversion + fold_out.
#define TPB 1250   // NN/16
#define WCB 336
__global__ void prep_misc(const float* __restrict__ x, unsigned short* __restrict__ xTs,
                          const float* Wg0, const float* Wu0, const float* Wr0, const float* Wc0,
                          const float* Wg1, const float* Wu1, const float* Wr1, const float* Wc1,
                          const float* ipw,
                          short* Wg0T, short* Wu0T, short* Wr0T, short* Wc0T,
                          short* Wg1T, short* Wu1T, short* Wr1T, short* Wc1T, short* ipwB,
                          const float* opw, const float* opb, const float* ow, const float* ob,
                          float* OW2, float* ob2) {
    int b = blockIdx.x;
    if (b < TPB) {
        __shared__ float tl[16 * 416];    // [nn][f*13 + t], 26.6 KB
        int n0 = b * 16;
        const float* xb = x + (size_t)n0 * 384;
        int tid = threadIdx.x;
        #pragma unroll
        for (int k = 0; k < 24; ++k) {
            int i = tid + 256 * k;                 // i < 6144
            float v = xb[i];
            int nn = i / 384;
            int rem = i - nn * 384;
            int f = rem / 12;
            int t2 = rem - f * 12;
            tl[nn * 416 + f * 13 + t2] = v;
        }
        __syncthreads();
        #pragma unroll
        for (int k = 0; k < 24; ++k) {
            int o = tid + 256 * k;
            int f = o & 31;
            int nn = (o >> 5) & 15;
            int t = o >> 9;
            xTs[(size_t)t * (NN * FF) + (size_t)(n0 + nn) * 32 + f] =
                bf16rne(tl[nn * 416 + f * 13 + t]);
        }
        return;
    }
    if (b < TPB + WCB) {
        int i = (b - TPB) * 256 + threadIdx.x;
        if (i < 2048) { int n = i / 32, k = i % 32; Wg0T[i] = (short)bf16rne(Wg0[k * 64 + n]); return; }
        i -= 2048;
        if (i < 10240) { int n = i / 160, k = i % 160; Wu0T[i] = (short)bf16rne(Wu0[k * 64 + n]); return; }
        i -= 10240;
        if (i < 10240) { int n = i / 160, k = i % 160; Wr0T[i] = (short)bf16rne(Wr0[k * 64 + n]); return; }
        i -= 10240;
        if (i < 10240) { int n = i / 160, k = i % 160; Wc0T[i] = (short)bf16rne(Wc0[k * 64 + n]); return; }
        i -= 10240;
        if (i < 4096) { int n = i / 64, k = i % 64; Wg1T[i] = (short)bf16rne(Wg1[k * 64 + n]); return; }
        i -= 4096;
        if (i < 12288) { int n = i / 192, k = i % 192; Wu1T[i] = (short)bf16rne(Wu1[k * 64 + n]); return; }
        i -= 12288;
        if (i < 12288) { int n = i / 192, k = i % 192; Wr1T[i] = (short)bf16rne(Wr1[k * 64 + n]); return; }
        i -= 12288;
        if (i < 12288) { int n = i / 192, k = i % 192; Wc1T[i] = (short)bf16rne(Wc1[k * 64 + n]); return; }
        i -= 12288;
        if (i < 12288) { ipwB[i] = (short)bf16rne(ipw[i]); }
        return;
    }
    {
        int i = (b - TPB - WCB) * 256 + threadIdx.x;
        if (i < 64 * OUTD) {
            int k = i / OUTD, d = i - k * OUTD;
            float acc = 0.f;
            for (int j = 0; j < 64; ++j) acc += opw[j * 64 + k] * ow[j * OUTD + d];
            OW2[i] = acc;
        } else if (i < 64 * OUTD + OUTD) {
            int d = i - 64 * OUTD;
            float acc = ob[d];
            for (int j = 0; j < 64; ++j) acc += opb[j] * ow[j * OUTD + d];
            ob2[d] = acc;
        }
    }
}

// bf16 aggregation over x planes: 16 lanes/node; unroll-8 (independent load batches)
__global__ void gather_raw32(const unsigned short* __restrict__ xTs, const float* __restrict__ dinv,
                             const int* __restrict__ rowptr, const int2* __restrict__ colval,
                             unsigned short* __restrict__ aggxs) {
    const unsigned* src = (const unsigned*)(xTs + (size_t)blockIdx.y * NN * 32);
    unsigned* dst = (unsigned*)(aggxs + (size_t)blockIdx.y * NN * 32);
    int node = blockIdx.x * 16 + (threadIdx.x >> 4);
    int l2 = threadIdx.x & 15;
    float di = dinv[node];
    float dd = di * di;
    unsigned v = src[node * 16 + l2];
    float a0 = dd * lof(v), a1 = dd * hif(v);
    int s = rowptr[node], e = rowptr[node + 1];
    int j = s;
    for (; j + 7 < e; j += 8) {
        int2 c[8];
        #pragma unroll
        for (int q = 0; q < 8; ++q) c[q] = colval[j + q];
        unsigned vv[8];
        #pragma unroll
        for (int q = 0; q < 8; ++q) vv[q] = src[c[q].x * 16 + l2];
        #pragma unroll
        for (int q = 0; q < 8; ++q) {
            float w = __int_as_float(c[q].y);
            a0 += w * lof(vv[q]); a1 += w * hif(vv[q]);
        }
    }
    for (; j + 3 < e; j += 4) {
        int2 cv0 = colval[j], cv1 = colval[j + 1], cv2 = colval[j + 2], cv3 = colval[j + 3];
        float w0 = __int_as_float(cv0.y), w1 = __int_as_float(cv1.y);
        float w2 = __int_as_float(cv2.y), w3 = __int_as_float(cv3.y);
        unsigned v0 = src[cv0.x * 16 + l2], v1 = src[cv1.x * 16 + l2];
        unsigned v2 = src[cv2.x * 16 + l2], v3 = src[cv3.x * 16 + l2];
        a0 += w0 * lof(v0) + w1 * lof(v1) + w2 * lof(v2) + w3 * lof(v3);
        a1 += w0 * hif(v0) + w1 * hif(v1) + w2 * hif(v2) + w3 * hif(v3);
    }
    for (; j < e; ++j) {
        int2 cv = colval[j];
        unsigned vv = src[cv.x * 16 + l2];
        float w = __int_as_float(cv.y);
        a0 += w * lof(vv); a1 += w * hif(vv);
    }
    dst[node * 16 + l2] = packbf(a0, a1);
}

// gather y0 + sigmoid -> g1: 32 lanes/node, unroll-8
__device__ __forceinline__ void gather_g1_body(
    int blk, const unsigned short* __restrict__ y0s, const float* __restrict__ dinv,
    const int* __restrict__ rowptr, const int2* __restrict__ colval,
    const float* __restrict__ bg1, unsigned short* __restrict__ g1s) {
    const unsigned* yp = (const unsigned*)y0s;
    int node = blk * 8 + (threadIdx.x >> 5);
    int l2 = threadIdx.x & 31;
    float di = dinv[node];
    float dd = di * di;
    unsigned v = yp[node * 32 + l2];
    float a0 = dd * lof(v), a1 = dd * hif(v);
    int s = rowptr[node], e = rowptr[node + 1];
    int j = s;
    for (; j + 7 < e; j += 8) {
        int2 c[8];
        #pragma unroll
        for (int q = 0; q < 8; ++q) c[q] = colval[j + q];
        unsigned vv[8];
        #pragma unroll
        for (int q = 0; q < 8; ++q) vv[q] = yp[c[q].x * 32 + l2];
        #pragma unroll
        for (int q = 0; q < 8; ++q) {
            float w = __int_as_float(c[q].y);
            a0 += w * lof(vv[q]); a1 += w * hif(vv[q]);
        }
    }
    for (; j + 3 < e; j += 4) {
        int2 cv0 = colval[j], cv1 = colval[j + 1], cv2 = colval[j + 2], cv3 = colval[j + 3];
        float w0 = __int_as_float(cv0.y), w1 = __int_as_float(cv1.y);
        float w2 = __int_as_float(cv2.y), w3 = __int_as_float(cv3.y);
        unsigned v0 = yp[cv0.x * 32 + l2], v1 = yp[cv1.x * 32 + l2];
        unsigned v2 = yp[cv2.x * 32 + l2], v3 = yp[cv3.x * 32 + l2];
        a0 += w0 * lof(v0) + w1 * lof(v1) + w2 * lof(v2) + w3 * lof(v3);
        a1 += w0 * hif(v0) + w1 * hif(v1) + w2 * hif(v2) + w3 * hif(v3);
    }
    for (; j < e; ++j) {
        int2 cv = colval[j];
        unsigned vv = yp[cv.x * 32 + l2];
        float w = __int_as_float(cv.y);
        a0 += w * lof(vv); a1 += w * hif(vv);
    }
    float g0v = fsig(a0 + bg1[2 * l2]);
    float g1v = fsig(a1 + bg1[2 * l2 + 1]);
    ((unsigned*)g1s)[node * 32 + l2] = packbf(g0v, g1v);
}

// ---------------- MFMA kernels ----------------
// A[m=lane&15][k=quad*8+j]; B^T[n=lane&15][k=quad*8+j]; C/D: col=lane&15, row=quad*4+reg.

__launch_bounds__(256, 4)
__global__ void mfma_g0(const unsigned short* __restrict__ aggxs, const short* __restrict__ Wg0T,
                        const float* __restrict__ bg0, unsigned short* __restrict__ g0s) {
    int tid = threadIdx.x;
    int wv = tid >> 6, lane = tid & 63;
    int quad = lane >> 4, ln = lane & 15;
    int m0 = blockIdx.x * 64 + wv * 16;
    short8 af = *reinterpret_cast<const short8*>(aggxs + (size_t)(m0 + ln) * 32 + quad * 8);
    floatx4 z = {0.f, 0.f, 0.f, 0.f};
    floatx4 acc[4] = {z, z, z, z};
    #pragma unroll
    for (int ct = 0; ct < 4; ++ct) {
        short8 bf = *reinterpret_cast<const short8*>(Wg0T + (size_t)(ct * 16 + ln) * 32 + quad * 8);
        acc[ct] = MFMA(af, bf, acc[ct]);
    }
    #pragma unroll
    for (int ct = 0; ct < 4; ++ct) {
        int col = ct * 16 + ln;
        float bb = bg0[col];
        #pragma unroll
        for (int r = 0; r < 4; ++r) {
            int row = m0 + quad * 4 + r;
            g0s[(size_t)row * 64 + col] = bf16rne(fsig(acc[ct][r] + bb));
        }
    }
}

// ---- cell bodies: 2 row-tiles per wave (32 rows/block), col-split across waves. ----

__device__ __forceinline__ void cell0_body(
    int m0, short* T,
    const unsigned short* __restrict__ xt, const unsigned short* __restrict__ g0,
    const unsigned short* __restrict__ h0s,
    const short* __restrict__ Wu0T, const short* __restrict__ Wr0T,
    const short* __restrict__ Wc0T, const short* __restrict__ Wg1T,
    const float* __restrict__ bu0, const float* __restrict__ br0,
    const float* __restrict__ bc0,
    unsigned short* __restrict__ h0ns, unsigned short* __restrict__ y0s) {
    int tid = threadIdx.x;
    int wv = tid >> 6, lane = tid & 63;
    int quad = lane >> 4, ln = lane & 15;
    int col = wv * 16 + ln;
    int a0r = m0 + ln, a1r = m0 + 16 + ln;

    short8 af0[5], af1[5];
    af0[0] = *reinterpret_cast<const short8*>(xt + (size_t)a0r * 32 + quad * 8);
    af1[0] = *reinterpret_cast<const short8*>(xt + (size_t)a1r * 32 + quad * 8);
    af0[1] = *reinterpret_cast<const short8*>(g0 + (size_t)a0r * 64 + quad * 8);
    af1[1] = *reinterpret_cast<const short8*>(g0 + (size_t)a1r * 64 + quad * 8);
    af0[2] = *reinterpret_cast<const short8*>(g0 + (size_t)a0r * 64 + 32 + quad * 8);
    af1[2] = *reinterpret_cast<const short8*>(g0 + (size_t)a1r * 64 + 32 + quad * 8);
    af0[3] = *reinterpret_cast<const short8*>(h0s + (size_t)a0r * 64 + quad * 8);
    af1[3] = *reinterpret_cast<const short8*>(h0s + (size_t)a1r * 64 + quad * 8);
    af0[4] = *reinterpret_cast<const short8*>(h0s + (size_t)a0r * 64 + 32 + quad * 8);
    af1[4] = *reinterpret_cast<const short8*>(h0s + (size_t)a1r * 64 + 32 + quad * 8);

    floatx4 z = {0.f, 0.f, 0.f, 0.f};
    floatx4 aU0 = z, aR0 = z, aU1 = z, aR1 = z;
    const short* bu = Wu0T + (size_t)col * 160;
    const short* br = Wr0T + (size_t)col * 160;
    #pragma unroll
    for (int kc = 0; kc < 5; ++kc) {
        int ko = kc * 32 + quad * 8;
        short8 wu = *reinterpret_cast<const short8*>(bu + ko);
        short8 wr = *reinterpret_cast<const short8*>(br + ko);
        aU0 = MFMA(af0[kc], wu, aU0);
        aU1 = MFMA(af1[kc], wu, aU1);
        aR0 = MFMA(af0[kc], wr, aR0);
        aR1 = MFMA(af1[kc], wr, aR1);
    }
    float bU = bu0[col], bR = br0[col];
    float uu0[4], hv0[4], uu1[4], hv1[4];
    #pragma unroll
    for (int r = 0; r < 4; ++r) {
        int g0r = m0 + quad * 4 + r, g1r = m0 + 16 + quad * 4 + r;
        uu0[r] = fsig(aU0[r] + bU);
        uu1[r] = fsig(aU1[r] + bU);
        hv0[r] = lof((unsigned)h0s[(size_t)g0r * 64 + col]);
        hv1[r] = lof((unsigned)h0s[(size_t)g1r * 64 + col]);
        T[(quad * 4 + r) * 72 + col] = (short)bf16rne(fsig(aR0[r] + bR) * hv0[r]);
        T[(16 + quad * 4 + r) * 72 + col] = (short)bf16rne(fsig(aR1[r] + bR) * hv1[r]);
    }
    __syncthreads();

    short8 p00 = *reinterpret_cast<const short8*>(T + ln * 72 + quad * 8);
    short8 p01 = *reinterpret_cast<const short8*>(T + ln * 72 + 32 + quad * 8);
    short8 p10 = *reinterpret_cast<const short8*>(T + (16 + ln) * 72 + quad * 8);
    short8 p11 = *reinterpret_cast<const short8*>(T + (16 + ln) * 72 + 32 + quad * 8);
    floatx4 aC0 = z, aC1 = z;
    const short* bc = Wc0T + (size_t)col * 160;
    #pragma unroll
    for (int kc = 0; kc < 3; ++kc) {
        short8 wc = *reinterpret_cast<const short8*>(bc + kc * 32 + quad * 8);
        aC0 = MFMA(af0[kc], wc, aC0);
        aC1 = MFMA(af1[kc], wc, aC1);
    }
    {
        short8 wc3 = *reinterpret_cast<const short8*>(bc + 96 + quad * 8);
        short8 wc4 = *reinterpret_cast<const short8*>(bc + 128 + quad * 8);
        aC0 = MFMA(p00, wc3, aC0);
        aC1 = MFMA(p10, wc3, aC1);
        aC0 = MFMA(p01, wc4, aC0);
        aC1 = MFMA(p11, wc4, aC1);
    }
    __syncthreads();   // all rh reads complete before T is overwritten with h_new

    float bC = bc0[col];
    #pragma unroll
    for (int r = 0; r < 4; ++r) {
        int g0r = m0 + quad * 4 + r, g1r = m0 + 16 + quad * 4 + r;
        float hn0 = uu0[r] * hv0[r] + (1.f - uu0[r]) * ftanh(aC0[r] + bC);
        float hn1 = uu1[r] * hv1[r] + (1.f - uu1[r]) * ftanh(aC1[r] + bC);
        unsigned short hb0 = bf16rne(hn0), hb1 = bf16rne(hn1);
        h0ns[(size_t)g0r * 64 + col] = hb0;
        h0ns[(size_t)g1r * 64 + col] = hb1;
        T[(quad * 4 + r) * 72 + col] = (short)hb0;
        T[(16 + quad * 4 + r) * 72 + col] = (short)hb1;
    }
    __syncthreads();

    short8 h00 = *reinterpret_cast<const short8*>(T + ln * 72 + quad * 8);
    short8 h01 = *reinterpret_cast<const short8*>(T + ln * 72 + 32 + quad * 8);
    short8 h10 = *reinterpret_cast<const short8*>(T + (16 + ln) * 72 + quad * 8);
    short8 h11 = *reinterpret_cast<const short8*>(T + (16 + ln) * 72 + 32 + quad * 8);
    floatx4 aY0 = z, aY1 = z;
    const short* bg = Wg1T + (size_t)col * 64;
    {
        short8 w0 = *reinterpret_cast<const short8*>(bg + quad * 8);
        short8 w1 = *reinterpret_cast<const short8*>(bg + 32 + quad * 8);
        aY0 = MFMA(h00, w0, aY0);
        aY1 = MFMA(h10, w0, aY1);
        aY0 = MFMA(h01, w1, aY0);
        aY1 = MFMA(h11, w1, aY1);
    }
    #pragma unroll
    for (int r = 0; r < 4; ++r) {
        int g0r = m0 + quad * 4 + r, g1r = m0 + 16 + quad * 4 + r;
        y0s[(size_t)g0r * 64 + col] = bf16rne(aY0[r]);
        y0s[(size_t)g1r * 64 + col] = bf16rne(aY1[r]);
    }
}

// cell1: h1 bf16 state lives in hseqsT (node-major, stride HST); in = slot t, out = slot t+1
__device__ __forceinline__ void cell1_body(
    int m0, short* T,
    const unsigned short* __restrict__ h0s, const unsigned short* __restrict__ g1s,
    const unsigned short* __restrict__ h1sT_in,
    const short* __restrict__ Wu1T, const short* __restrict__ Wr1T,
    const short* __restrict__ Wc1T,
    const float* __restrict__ bu1, const float* __restrict__ br1,
    const float* __restrict__ bc1,
    unsigned short* __restrict__ h1sT_out) {
    int tid = threadIdx.x;
    int wv = tid >> 6, lane = tid & 63;
    int quad = lane >> 4, ln = lane & 15;
    int col = wv * 16 + ln;
    int a0r = m0 + ln, a1r = m0 + 16 + ln;

    short8 af0[6], af1[6];
    af0[0] = *reinterpret_cast<const short8*>(h0s + (size_t)a0r * 64 + quad * 8);
    af1[0] = *reinterpret_cast<const short8*>(h0s + (size_t)a1r * 64 + quad * 8);
    af0[1] = *reinterpret_cast<const short8*>(h0s + (size_t)a0r * 64 + 32 + quad * 8);
    af1[1] = *reinterpret_cast<const short8*>(h0s + (size_t)a1r * 64 + 32 + quad * 8);
    af0[2] = *reinterpret_cast<const short8*>(g1s + (size_t)a0r * 64 + quad * 8);
    af1[2] = *reinterpret_cast<const short8*>(g1s + (size_t)a1r * 64 + quad * 8);
    af0[3] = *reinterpret_cast<const short8*>(g1s + (size_t)a0r * 64 + 32 + quad * 8);
    af1[3] = *reinterpret_cast<const short8*>(g1s + (size_t)a1r * 64 + 32 + quad * 8);
    af0[4] = *reinterpret_cast<const short8*>(h1sT_in + (size_t)a0r * HST + quad * 8);
    af1[4] = *reinterpret_cast<const short8*>(h1sT_in + (size_t)a1r * HST + quad * 8);
    af0[5] = *reinterpret_cast<const short8*>(h1sT_in + (size_t)a0r * HST + 32 + quad * 8);
    af1[5] = *reinterpret_cast<const short8*>(h1sT_in + (size_t)a1r * HST + 32 + quad * 8);

    floatx4 z = {0.f, 0.f, 0.f, 0.f};
    floatx4 aU0 = z, aR0 = z, aU1 = z, aR1 = z;
    const short* bu = Wu1T + (size_t)col * 192;
    const short* br = Wr1T + (size_t)col * 192;
    #pragma unroll
    for (int kc = 0; kc < 6; ++kc) {
        int ko = kc * 32 + quad * 8;
        short8 wu = *reinterpret_cast<const short8*>(bu + ko);
        short8 wr = *reinterpret_cast<const short8*>(br + ko);
        aU0 = MFMA(af0[kc], wu, aU0);
        aU1 = MFMA(af1[kc], wu, aU1);
        aR0 = MFMA(af0[kc], wr, aR0);
        aR1 = MFMA(af1[kc], wr, aR1);
    }
    float bU = bu1[col], bR = br1[col];
    float uu0[4], hv0[4], uu1[4], hv1[4];
    #pragma unroll
    for (int r = 0; r < 4; ++r) {
        int g0r = m0 + quad * 4 + r, g1r = m0 + 16 + quad * 4 + r;
        uu0[r] = fsig(aU0[r] + bU);
        uu1[r] = fsig(aU1[r] + bU);
        hv0[r] = lof((unsigned)h1sT_in[(size_t)g0r * HST + col]);
        hv1[r] = lof((unsigned)h1sT_in[(size_t)g1r * HST + col]);
        T[(quad * 4 + r) * 72 + col] = (short)bf16rne(fsig(aR0[r] + bR) * hv0[r]);
        T[(16 + quad * 4 + r) * 72 + col] = (short)bf16rne(fsig(aR1[r] + bR) * hv1[r]);
    }
    __syncthreads();

    short8 p00 = *reinterpret_cast<const short8*>(T + ln * 72 + quad * 8);
    short8 p01 = *reinterpret_cast<const short8*>(T + ln * 72 + 32 + quad * 8);
    short8 p10 = *reinterpret_cast<const short8*>(T + (16 + ln) * 72 + quad * 8);
    short8 p11 = *reinterpret_cast<const short8*>(T + (16 + ln) * 72 + 32 + quad * 8);
    floatx4 aC0 = z, aC1 = z;
    const short* bc = Wc1T + (size_t)col * 192;
    #pragma unroll
    for (int kc = 0; kc < 4; ++kc) {
        short8 wc = *reinterpret_cast<const short8*>(bc + kc * 32 + quad * 8);
        aC0 = MFMA(af0[kc], wc, aC0);
        aC1 = MFMA(af1[kc], wc, aC1);
    }
    {
        short8 wc4 = *reinterpret_cast<const short8*>(bc + 128 + quad * 8);
        short8 wc5 = *reinterpret_cast<const short8*>(bc + 160 + quad * 8);
        aC0 = MFMA(p00, wc4, aC0);
        aC1 = MFMA(p10, wc4, aC1);
        aC0 = MFMA(p01, wc5, aC0);
        aC1 = MFMA(p11, wc5, aC1);
    }

    float bC = bc1[col];
    #pragma unroll
    for (int r = 0; r < 4; ++r) {
        int g0r = m0 + quad * 4 + r, g1r = m0 + 16 + quad * 4 + r;
        float hn0 = uu0[r] * hv0[r] + (1.f - uu0[r]) * ftanh(aC0[r] + bC);
        float hn1 = uu1[r] * hv1[r] + (1.f - uu1[r]) * ftanh(aC1[r] + bC);
        h1sT_out[(size_t)g0r * HST + col] = bf16rne(hn0);
        h1sT_out[(size_t)g1r * HST + col] = bf16rne(hn1);
    }
}

// ---------------- 3-stage pipelined step, phase-INTERLEAVED grid ----------------
// Grid pattern (full launch): 625 groups of [C0, G,G,G,G, C1] so every resident
// cohort mixes MFMA-heavy cells with latency-bound gathers (co-scheduling overlap).

struct PipeArgs {
    const float* dinv; const int* rowptr; const int2* colval;
    const short* Wu0T; const short* Wr0T; const short* Wc0T; const short* Wg1T;
    const float* bu0; const float* br0; const float* bc0;
    const short* Wu1T; const short* Wr1T; const short* Wc1T;
    const float* bu1; const float* br1; const float* bc1; const float* bg1;
    int c0n;   // 625 or 0 (32-row tiles)
    const unsigned short* c0_xt; const unsigned short* c0_g0;
    const unsigned short* c0_hs_in;
    unsigned short* c0_hs_out; unsigned short* c0_y0_out;
    int gn;    // 2500 or 0
    const unsigned short* g_y0; unsigned short* g_g1;
    int c1n;   // 625 or 0
    const unsigned short* c1_h0s; const unsigned short* c1_g1;
    const unsigned short* c1_hsT_in;
    unsigned short* c1_hsT_out;
};

__launch_bounds__(256, 6)
__global__ void pipe_step(PipeArgs A) {
    __shared__ short T[32 * 72];
    int per = (A.c0n ? 1 : 0) + (A.gn ? 4 : 0) + (A.c1n ? 1 : 0);
    int q = blockIdx.x / per;
    int r = blockIdx.x - q * per;
    int goff = A.c0n ? 1 : 0;
    if (A.c0n && r == 0) {
        cell0_body(q * 32, T, A.c0_xt, A.c0_g0, A.c0_hs_in,
                   A.Wu0T, A.Wr0T, A.Wc0T, A.Wg1T, A.bu0, A.br0, A.bc0,
                   A.c0_hs_out, A.c0_y0_out);
        return;
    }
    if (A.gn && r >= goff && r < goff + 4) {
        gather_g1_body(q * 4 + (r - goff), A.g_y0, A.dinv, A.rowptr, A.colval, A.bg1, A.g_g1);
        return;
    }
    cell1_body(q * 32, T, A.c1_h0s, A.c1_g1, A.c1_hsT_in,
               A.Wu1T, A.Wr1T, A.Wc1T, A.bu1, A.br1, A.bc1,
               A.c1_hsT_out);
}

// ---------------- fused qkv + attention: one wave per node ----------------
__launch_bounds__(256, 6)
__global__ void attn_fused(const unsigned short* __restrict__ hseqT,
                           const short* __restrict__ ipwB, const float* __restrict__ ipb,
                           const float* __restrict__ OW2, const float* __restrict__ ob2,
                           float* __restrict__ out) {
    __shared__ __align__(16) unsigned short qtile[4][16 * QS];
    __shared__ float fbuf[4][64];
    __shared__ float wbuf[4][32];
    int wv = threadIdx.x >> 6, lane = threadIdx.x & 63;
    int node = blockIdx.x * 4 + wv;
    int quad = lane >> 4, ln = lane & 15;
    unsigned short* q = qtile[wv];
    float* sob = fbuf[wv];
    float* W = wbuf[wv];

    short8 zero8 = {0, 0, 0, 0, 0, 0, 0, 0};
    short8 af0 = zero8, af1 = zero8;
    if (ln < TT) {
        const unsigned short* hp = hseqT + (size_t)node * HST + (size_t)(ln + 1) * 64;
        af0 = *reinterpret_cast<const short8*>(hp + quad * 8);
        af1 = *reinterpret_cast<const short8*>(hp + 32 + quad * 8);
    }
    floatx4 z = {0.f, 0.f, 0.f, 0.f};
    #pragma unroll
    for (int ct = 0; ct < 12; ++ct) {
        const short* br = ipwB + (size_t)(ct * 16 + ln) * 64;
        floatx4 acc = MFMA(af0, *reinterpret_cast<const short8*>(br + quad * 8), z);
        acc = MFMA(af1, *reinterpret_cast<const short8*>(br + 32 + quad * 8), acc);
        int col = ct * 16 + ln;
        float bb = ipb[col];
        #pragma unroll
        for (int r = 0; r < 4; ++r)
            q[(quad * 4 + r) * QS + col] = bf16rne(acc[r] + bb);
    }
    __threadfence_block();

    floatx4 sc[2];
    #pragma unroll
    for (int h = 0; h < 2; ++h) {
        short8 aQ = *reinterpret_cast<const short8*>(q + ln * QS + h * 32 + quad * 8);
        short8 bK = *reinterpret_cast<const short8*>(q + ln * QS + 64 + h * 32 + quad * 8);
        sc[h] = MFMA(aQ, bK, z);
    }
    // softmax without max-subtraction (|h|<=1 by gating => |scores| bounded << 88)
    const float scl = 0.17677669529663687f;
    bool colok = ln < 12;
    #pragma unroll
    for (int h = 0; h < 2; ++h) {
        float p[4];
        #pragma unroll
        for (int r = 0; r < 4; ++r) {
            float e = colok ? aexp2(LOG2E * scl * sc[h][r]) : 0.f;
            float s = e;
            s += __shfl_xor(s, 1, 64);
            s += __shfl_xor(s, 2, 64);
            s += __shfl_xor(s, 4, 64);
            s += __shfl_xor(s, 8, 64);
            p[r] = e * arcp(s);
        }
        float ts = (quad < 3) ? (p[0] + p[1] + p[2] + p[3]) : 0.f;
        ts += __shfl_xor(ts, 16, 64);
        ts += __shfl_xor(ts, 32, 64);
        if (quad == 0) W[h * 16 + ln] = ts * (1.f / 12.f);
    }
    __threadfence_block();

    {
        int d = lane, hd = d >> 5, dd = d & 31;
        float acc = 0.f;
        #pragma unroll
        for (int ts = 0; ts < 12; ++ts)
            acc += W[hd * 16 + ts] * lof((unsigned)q[ts * QS + 128 + hd * 32 + dd]);
        sob[d] = acc;
    }
    __threadfence_block();

    // quad-split projection: quad covers k in [16*quad, 16*quad+16); reduce via 2 shuffles.
    {
        float acc = 0.f;
        if (ln < OUTD) {
            int k0 = quad * 16;
            #pragma unroll
            for (int k = 0; k < 16; ++k)
                acc = fmaf(sob[k0 + k], OW2[(k0 + k) * OUTD + ln], acc);
        }
        acc += __shfl_xor(acc, 16, 64);
        acc += __shfl_xor(acc, 32, 64);
        if (quad == 0 && ln < OUTD)
            out[(size_t)node * OUTD + ln] = acc + ob2[ln];
    }
}

// ---------------- launcher ----------------

extern "C" void kernel_launch(void* const* d_in, const int* in_sizes, int n_in,
                              void* d_out, int out_size, void* d_ws, size_t ws_size,
                              hipStream_t stream) {
    const float* x   = (const float*)d_in[0];
    const int*   ei  = (const int*)d_in[1];
    const float* ea  = (const float*)d_in[2];
    const float* Wg0 = (const float*)d_in[3];
    const float* bg0 = (const float*)d_in[4];
    const float* Wu0 = (const float*)d_in[5];
    const float* bu0 = (const float*)d_in[6];
    const float* Wr0 = (const float*)d_in[7];
    const float* br0 = (const float*)d_in[8];
    const float* Wc0 = (const float*)d_in[9];
    const float* bc0 = (const float*)d_in[10];
    const float* Wg1 = (const float*)d_in[11];
    const float* bg1 = (const float*)d_in[12];
    const float* Wu1 = (const float*)d_in[13];
    const float* bu1 = (const float*)d_in[14];
    const float* Wr1 = (const float*)d_in[15];
    const float* br1 = (const float*)d_in[16];
    const float* Wc1 = (const float*)d_in[17];
    const float* bc1 = (const float*)d_in[18];
    const float* ipw = (const float*)d_in[19];
    const float* ipb = (const float*)d_in[20];
    const float* opw = (const float*)d_in[21];
    const float* opb = (const float*)d_in[22];
    const float* ow  = (const float*)d_in[23];
    const float* ob  = (const float*)d_in[24];
    float* out = (float*)d_out;

    char* p = (char*)d_ws;
    auto alloc = [&](size_t bytes) { char* r = p; p += (bytes + 255) & ~(size_t)255; return (void*)r; };
    unsigned short* hseqT = (unsigned short*)alloc((size_t)NN * HST * 2);   // [node][13][64]
    short* Wg0T = (short*)alloc((size_t)64 * 32 * 2);
    short* Wu0T = (short*)alloc((size_t)64 * 160 * 2);
    short* Wr0T = (short*)alloc((size_t)64 * 160 * 2);
    short* Wc0T = (short*)alloc((size_t)64 * 160 * 2);
    short* Wg1T = (short*)alloc((size_t)64 * 64 * 2);
    short* Wu1T = (short*)alloc((size_t)64 * 192 * 2);
    short* Wr1T = (short*)alloc((size_t)64 * 192 * 2);
    short* Wc1T = (short*)alloc((size_t)64 * 192 * 2);
    short* ipwB = (short*)alloc((size_t)192 * 64 * 2);
    float* OW2  = (float*)alloc((size_t)64 * OUTD * 4);
    float* ob2  = (float*)alloc((size_t)OUTD * 4);
    float* dinv   = (float*)alloc((size_t)NN * 4);
    int*   rowptr = (int*)  alloc((size_t)(NN + 1) * 4);
    int2*  colval = (int2*) alloc((size_t)EE * 8);
    unsigned short* xTs   = (unsigned short*)alloc((size_t)TT * NN * FF * 2);
    unsigned short* aggxs = (unsigned short*)alloc((size_t)TT * NN * FF * 2);
    unsigned short* g0s   = (unsigned short*)alloc((size_t)TT * NN * HH * 2);
    float* deg    = (float*)alloc((size_t)NN * 4);
    int*   cnt    = (int*)  alloc((size_t)NN * 4);
    int*   cursor = (int*)  alloc((size_t)NN * 4);
    unsigned short* y0sA = (unsigned short*)alloc((size_t)NN * HH * 2);
    unsigned short* y0sB = (unsigned short*)alloc((size_t)NN * HH * 2);
    unsigned short* g1sA = (unsigned short*)alloc((size_t)NN * HH * 2);
    unsigned short* g1sB = (unsigned short*)alloc((size_t)NN * HH * 2);
    unsigned short* h0s0 = (unsigned short*)alloc((size_t)NN * HH * 2);
    unsigned short* h0s1 = (unsigned short*)alloc((size_t)NN * HH * 2);
    unsigned short* h0s2 = (unsigned short*)alloc((size_t)NN * HH * 2);
    (void)ws_size;

    init_all<<<(NN * HH + 255) / 256, 256, 0, stream>>>(
        deg, cnt, (unsigned*)h0s2, (unsigned*)hseqT);
    edge_accum_kernel<<<(EE + 255) / 256, 256, 0, stream>>>(ei, ea, deg, cnt);
    scan_dinv<<<1 + (NN + 1023) / 1024, 1024, 0, stream>>>(cnt, rowptr, cursor, deg, dinv);
    fill_kernel<<<(EE + 255) / 256, 256, 0, stream>>>(ei, ea, dinv, cursor, colval);
    prep_misc<<<TPB + WCB + 4, 256, 0, stream>>>(
        x, xTs,
        Wg0, Wu0, Wr0, Wc0, Wg1, Wu1, Wr1, Wc1, ipw,
        Wg0T, Wu0T, Wr0T, Wc0T, Wg1T, Wu1T, Wr1T, Wc1T, ipwB,
        opw, opb, ow, ob, OW2, ob2);

    gather_raw32<<<dim3(NN / 16, TT), 256, 0, stream>>>(xTs, dinv, rowptr, colval, aggxs);
    mfma_g0<<<(TT * NN) / 64, 256, 0, stream>>>(aggxs, Wg0T, bg0, g0s);

    unsigned short* h0sB[3] = {h0s0, h0s1, h0s2};
    unsigned short* y0B[2] = {y0sA, y0sB};
    unsigned short* g1B[2] = {g1sA, g1sB};

    PipeArgs base;
    base.dinv = dinv; base.rowptr = rowptr; base.colval = colval;
    base.Wu0T = Wu0T; base.Wr0T = Wr0T; base.Wc0T = Wc0T; base.Wg1T = Wg1T;
    base.bu0 = bu0; base.br0 = br0; base.bc0 = bc0;
    base.Wu1T = Wu1T; base.Wr1T = Wr1T; base.Wc1T = Wc1T;
    base.bu1 = bu1; base.br1 = br1; base.bc1 = bc1; base.bg1 = bg1;

    // pipeline: launch l = { C0(l), G(l-1), C1(l-2) }, l = 0..13
    for (int l = 0; l <= TT + 1; ++l) {
        PipeArgs A = base;
        int tc0 = l, tg = l - 1, tc1 = l - 2;

        A.c0n = (tc0 < TT) ? CT2 : 0;
        if (A.c0n) {
            A.c0_xt = xTs + (size_t)tc0 * NN * FF;
            A.c0_g0 = g0s + (size_t)tc0 * NN * HH;
            A.c0_hs_in = h0sB[(tc0 + 2) % 3];
            A.c0_hs_out = h0sB[tc0 % 3];
            A.c0_y0_out = y0B[tc0 & 1];
        } else {
            A.c0_xt = xTs; A.c0_g0 = g0s; A.c0_hs_in = h0sB[0];
            A.c0_hs_out = h0sB[0]; A.c0_y0_out = y0B[0];
        }

        A.gn = (tg >= 0 && tg < TT) ? GB : 0;
        if (A.gn) { A.g_y0 = y0B[tg & 1]; A.g_g1 = g1B[tg & 1]; }
        else { A.g_y0 = y0B[0]; A.g_g1 = g1B[0]; }

        A.c1n = (tc1 >= 0 && tc1 < TT) ? CT2 : 0;
        if (A.c1n) {
            A.c1_h0s = h0sB[tc1 % 3];
            A.c1_g1 = g1B[tc1 & 1];
            A.c1_hsT_in = hseqT + (size_t)tc1 * 64;         // slot(t-1) = tc1
            A.c1_hsT_out = hseqT + (size_t)(tc1 + 1) * 64;  // slot(t) = tc1+1
        } else {
            A.c1_h0s = h0sB[0]; A.c1_g1 = g1B[0];
            A.c1_hsT_in = hseqT; A.c1_hsT_out = hseqT;
        }

        int grid = A.c0n + A.gn + A.c1n;
        pipe_step<<<grid, 256, 0, stream>>>(A);
    }

    attn_fused<<<NN / 4, 256, 0, stream>>>(hseqT, ipwB, ipb, OW2, ob2, out);
}